// Round 1
// baseline (1433.979 us; speedup 1.0000x reference)
//
#include <hip/hip_runtime.h>
#include <hip/hip_bf16.h>
#include <stdint.h>

// Problem constants (from reference): H=2048, I=4096, E=8, TOPK=2, B*S=4096
#define H_DIM 2048
#define I_DIM 4096
#define NEXP  8
#define NTOK  4096
#define NPAIR 8192                 // NTOK * TOPK
#define PAD_ROWS (NPAIR + 128)     // pad so last 128-row tile of last expert stays in-bounds

// Workspace layout (bytes)
#define MiB (1024ull * 1024ull)
#define WS_COUNTS   0ull
#define WS_OFFSETS  256ull
#define WS_TOKID    1024ull                 // NPAIR ints (32 KB)
#define WS_SLOT     (64ull * 1024)          // NPAIR ints: slotOf[pair] (32 KB)
#define WS_PAIRW    (128ull * 1024)         // NPAIR floats (32 KB)
#define WS_XG       (1ull * MiB)            // PAD_ROWS * H * 2B = 34.1 MB
#define WS_INTER    (36ull * MiB)           // PAD_ROWS * I * 2B = 68.2 MB
#define WS_Y        (104ull * MiB)          // PAD_ROWS * H * 4B = 68.2 MB (per-pair down output)
#define WS_GW       (176ull * MiB)          // E*I*H bf16 = 128 MiB
#define WS_UW       (304ull * MiB)          // 128 MiB
#define WS_DW       (432ull * MiB)          // 128 MiB
#define WS_FULL     (560ull * MiB)
#define WS_MIN_NEEDED (WS_INTER + (unsigned long long)PAD_ROWS * I_DIM * 2)

typedef __attribute__((ext_vector_type(8))) short bf16x8;   // 8 bf16 = 4 VGPRs (MFMA A/B frag)
typedef __attribute__((ext_vector_type(4))) float f32x4;    // MFMA C/D frag

#if defined(__has_builtin)
#if __has_builtin(__builtin_amdgcn_cvt_pk_bf16_f32)
#define HAVE_CVT_PK 1
#endif
#endif

__device__ __forceinline__ uint32_t bf16_bits_rne(float x) {
  uint32_t u = __float_as_uint(x);
  return (u + 0x7FFFu + ((u >> 16) & 1u)) >> 16;
}

__device__ __forceinline__ uint32_t pk_bf16(float a, float b) {
#ifdef HAVE_CVT_PK
  auto r = __builtin_amdgcn_cvt_pk_bf16_f32(a, b);   // v_cvt_pk_bf16_f32 (RNE), 1 instr / 2 elems
  return __builtin_bit_cast(uint32_t, r);
#else
  return bf16_bits_rne(a) | (bf16_bits_rne(b) << 16);
#endif
}

__device__ __forceinline__ uint16_t bf16_one(float x) {
  return (uint16_t)(pk_bf16(x, x) & 0xFFFFu);
}

// async global->LDS, 16B per lane; lds base must be wave-uniform, lane i lands at base + 16*i
__device__ __forceinline__ void async_load16(const void* g, void* l) {
  __builtin_amdgcn_global_load_lds(
      (const __attribute__((address_space(1))) void*)g,
      (__attribute__((address_space(3))) void*)l, 16, 0, 0);
}

// ---------------- routing: counts, offsets, scatter (token_id, pair_w, slotOf) ----------------
__global__ void route_kernel(const int* __restrict__ idx, const float* __restrict__ wts,
                             int* __restrict__ ws_counts, int* __restrict__ ws_offsets,
                             int* __restrict__ tokid, int* __restrict__ slotOf,
                             float* __restrict__ pairw) {
  __shared__ int s_cnt[NEXP], s_off[NEXP], s_cur[NEXP];
  int tid = threadIdx.x;
  if (tid < NEXP) s_cnt[tid] = 0;
  __syncthreads();
  for (int p = tid; p < NPAIR; p += 256) atomicAdd(&s_cnt[idx[p]], 1);
  __syncthreads();
  if (tid == 0) {
    int acc = 0;
    for (int e = 0; e < NEXP; e++) { s_off[e] = acc; s_cur[e] = acc; acc += s_cnt[e]; }
  }
  __syncthreads();
  for (int p = tid; p < NPAIR; p += 256) {
    int e = idx[p];
    int slot = atomicAdd(&s_cur[e], 1);     // slot already includes expert base offset
    tokid[slot] = p >> 1;                   // TOPK = 2
    slotOf[p] = slot;                       // inverse map for atomic-free combine
    pairw[slot] = wts[p];
  }
  if (tid < NEXP) { ws_counts[tid] = s_cnt[tid]; ws_offsets[tid] = s_off[tid]; }
}

// ---------------- gather routed rows of x, fp32 -> bf16 ----------------
__global__ void gather_cast_kernel(const float* __restrict__ x, const int* __restrict__ tokid,
                                   uint16_t* __restrict__ xg) {
  int p = blockIdx.x;                  // routed row
  int t = tokid[p];
  int c = threadIdx.x * 8;             // 256 threads * 8 = 2048 = H
  const float4* src = (const float4*)(x + (size_t)t * H_DIM + c);
  float4 v0 = src[0], v1 = src[1];
  uint4 o;
  o.x = pk_bf16(v0.x, v0.y); o.y = pk_bf16(v0.z, v0.w);
  o.z = pk_bf16(v1.x, v1.y); o.w = pk_bf16(v1.z, v1.w);
  *(uint4*)(xg + (size_t)p * H_DIM + c) = o;
}

// ---------------- one-shot weight cast: fp32 -> bf16 for gate/up/down ----------------
__global__ void cast3_kernel(const float* __restrict__ g, const float* __restrict__ u,
                             const float* __restrict__ d,
                             uint16_t* __restrict__ gw, uint16_t* __restrict__ uw,
                             uint16_t* __restrict__ dw) {
  const float* src = blockIdx.y == 0 ? g : (blockIdx.y == 1 ? u : d);
  uint16_t*    dst = blockIdx.y == 0 ? gw : (blockIdx.y == 1 ? uw : dw);
  const long long n8 = (long long)NEXP * I_DIM * H_DIM / 8;   // 8 bf16 per iter
  long long stride = (long long)gridDim.x * blockDim.x;
  for (long long i = (long long)blockIdx.x * blockDim.x + threadIdx.x; i < n8; i += stride) {
    const float4* s = (const float4*)(src + i * 8);
    float4 a = s[0], b = s[1];
    uint4 o = { pk_bf16(a.x, a.y), pk_bf16(a.z, a.w), pk_bf16(b.x, b.y), pk_bf16(b.z, b.w) };
    *(uint4*)(dst + i * 8) = o;
  }
}

// ---------------- GEMM1 (pre-converted B): pure global_load_lds staging ----------------
// block 256 = 4 waves (2x2 of 64x64), tile 128x128, BK=64
__global__ __launch_bounds__(256, 2)
void gemm1_pre_kernel(const uint16_t* __restrict__ xg,
                      const uint16_t* __restrict__ gw, const uint16_t* __restrict__ uw,
                      const int* __restrict__ ws_counts, const int* __restrict__ ws_offsets,
                      uint16_t* __restrict__ inter) {
  int e = blockIdx.z;
  int cnt = ws_counts[e];
  int rowTile = blockIdx.y;
  if (rowTile * 128 >= cnt) return;
  int off = ws_offsets[e];
  int colBase = blockIdx.x * 128;
  size_t rowBase = (size_t)off + (size_t)rowTile * 128;

  __shared__ uint16_t lA[128 * 64];
  __shared__ uint16_t lBg[128 * 64];
  __shared__ uint16_t lBu[128 * 64];

  int tid = threadIdx.x;
  int lane = tid & 63, wid = tid >> 6;
  int wm = (wid & 1) * 64, wn = (wid >> 1) * 64;
  int lcol = lane & 15, quad = lane >> 4;

  const uint16_t* gwb = gw + ((size_t)e * I_DIM + colBase) * H_DIM;
  const uint16_t* uwb = uw + ((size_t)e * I_DIM + colBase) * H_DIM;

  f32x4 accg[4][4], accu[4][4];
  f32x4 zero = {0.f, 0.f, 0.f, 0.f};
#pragma unroll
  for (int mi = 0; mi < 4; mi++)
#pragma unroll
    for (int ni = 0; ni < 4; ni++) { accg[mi][ni] = zero; accu[mi][ni] = zero; }

  for (int k0 = 0; k0 < H_DIM; k0 += 64) {
    __syncthreads();
#pragma unroll
    for (int rd = 0; rd < 4; rd++) {
      int chunkBase = rd * 256 + wid * 64;           // wave-uniform
      int chunk = chunkBase + lane;
      int row = chunk >> 3, kc = (chunk & 7) * 8;
      size_t goff = (size_t)row * H_DIM + k0 + kc;
      async_load16(xg + (rowBase + row) * H_DIM + k0 + kc, lA + chunkBase * 8);
      async_load16(gwb + goff, lBg + chunkBase * 8);
      async_load16(uwb + goff, lBu + chunkBase * 8);
    }
    __syncthreads();
#pragma unroll
    for (int ks = 0; ks < 64; ks += 32) {
      int krow = ks + quad * 8;
      bf16x8 af[4], bg[4], bu[4];
#pragma unroll
      for (int mi = 0; mi < 4; mi++)
        af[mi] = *(const bf16x8*)(lA + (wm + mi * 16 + lcol) * 64 + krow);
#pragma unroll
      for (int ni = 0; ni < 4; ni++) {
        bg[ni] = *(const bf16x8*)(lBg + (wn + ni * 16 + lcol) * 64 + krow);
        bu[ni] = *(const bf16x8*)(lBu + (wn + ni * 16 + lcol) * 64 + krow);
      }
#pragma unroll
      for (int mi = 0; mi < 4; mi++)
#pragma unroll
        for (int ni = 0; ni < 4; ni++) {
          accg[mi][ni] = __builtin_amdgcn_mfma_f32_16x16x32_bf16(af[mi], bg[ni], accg[mi][ni], 0, 0, 0);
          accu[mi][ni] = __builtin_amdgcn_mfma_f32_16x16x32_bf16(af[mi], bu[ni], accu[mi][ni], 0, 0, 0);
        }
    }
  }
  // epilogue: silu(g)*u -> bf16 inter.  C layout: col=lane&15, row=quad*4+reg
  int col0 = colBase + wn;
#pragma unroll
  for (int mi = 0; mi < 4; mi++) {
#pragma unroll
    for (int r = 0; r < 4; r++) {
      int localRow = rowTile * 128 + wm + mi * 16 + quad * 4 + r;
      if (localRow < cnt) {
        size_t prow = (size_t)off + localRow;
#pragma unroll
        for (int ni = 0; ni < 4; ni++) {
          float g = accg[mi][ni][r], u = accu[mi][ni][r];
          float v = (g / (1.f + __expf(-g))) * u;
          inter[prow * I_DIM + col0 + ni * 16 + lcol] = bf16_one(v);
        }
      }
    }
  }
}

// ---------------- GEMM2 (pre-converted B): plain stores to per-pair y, no atomics ----------------
__global__ __launch_bounds__(256, 2)
void gemm2_pre_kernel(const uint16_t* __restrict__ inter, const uint16_t* __restrict__ dw,
                      const int* __restrict__ ws_counts, const int* __restrict__ ws_offsets,
                      const float* __restrict__ pairw, float* __restrict__ y) {
  int e = blockIdx.z;
  int cnt = ws_counts[e];
  int rowTile = blockIdx.y;
  if (rowTile * 128 >= cnt) return;
  int off = ws_offsets[e];
  int colBase = blockIdx.x * 128;
  size_t rowBase = (size_t)off + (size_t)rowTile * 128;

  __shared__ uint16_t lA[128 * 64];
  __shared__ uint16_t lB[128 * 64];

  int tid = threadIdx.x;
  int lane = tid & 63, wid = tid >> 6;
  int wm = (wid & 1) * 64, wn = (wid >> 1) * 64;
  int lcol = lane & 15, quad = lane >> 4;

  const uint16_t* dwb = dw + ((size_t)e * H_DIM + colBase) * I_DIM;

  f32x4 acc[4][4];
  f32x4 zero = {0.f, 0.f, 0.f, 0.f};
#pragma unroll
  for (int mi = 0; mi < 4; mi++)
#pragma unroll
    for (int ni = 0; ni < 4; ni++) acc[mi][ni] = zero;

  for (int k0 = 0; k0 < I_DIM; k0 += 64) {
    __syncthreads();
#pragma unroll
    for (int rd = 0; rd < 4; rd++) {
      int chunkBase = rd * 256 + wid * 64;
      int chunk = chunkBase + lane;
      int row = chunk >> 3, kc = (chunk & 7) * 8;
      async_load16(inter + (rowBase + row) * I_DIM + k0 + kc, lA + chunkBase * 8);
      async_load16(dwb + (size_t)row * I_DIM + k0 + kc, lB + chunkBase * 8);
    }
    __syncthreads();
#pragma unroll
    for (int ks = 0; ks < 64; ks += 32) {
      int krow = ks + quad * 8;
      bf16x8 af[4], bf[4];
#pragma unroll
      for (int mi = 0; mi < 4; mi++)
        af[mi] = *(const bf16x8*)(lA + (wm + mi * 16 + lcol) * 64 + krow);
#pragma unroll
      for (int ni = 0; ni < 4; ni++)
        bf[ni] = *(const bf16x8*)(lB + (wn + ni * 16 + lcol) * 64 + krow);
#pragma unroll
      for (int mi = 0; mi < 4; mi++)
#pragma unroll
        for (int ni = 0; ni < 4; ni++)
          acc[mi][ni] = __builtin_amdgcn_mfma_f32_16x16x32_bf16(af[mi], bf[ni], acc[mi][ni], 0, 0, 0);
    }
  }
  int col0 = colBase + wn;
#pragma unroll
  for (int mi = 0; mi < 4; mi++) {
#pragma unroll
    for (int r = 0; r < 4; r++) {
      int localRow = rowTile * 128 + wm + mi * 16 + quad * 4 + r;
      if (localRow < cnt) {
        size_t prow = (size_t)off + localRow;
        float w = pairw[prow];
        float* yr = y + prow * H_DIM + col0;
#pragma unroll
        for (int ni = 0; ni < 4; ni++)
          yr[ni * 16 + lcol] = acc[mi][ni][r] * w;
      }
    }
  }
}

// ---------------- combine: out[t] = y[slot(2t)] + y[slot(2t+1)] ----------------
__global__ void combine_kernel(const float* __restrict__ y, const int* __restrict__ slotOf,
                               float* __restrict__ out) {
  int t = blockIdx.x;
  int s0 = slotOf[2 * t], s1 = slotOf[2 * t + 1];
  int c = threadIdx.x * 8;
  const float4* a = (const float4*)(y + (size_t)s0 * H_DIM + c);
  const float4* b = (const float4*)(y + (size_t)s1 * H_DIM + c);
  float4 a0 = a[0], a1 = a[1], b0 = b[0], b1 = b[1];
  float4 o0 = {a0.x + b0.x, a0.y + b0.y, a0.z + b0.z, a0.w + b0.w};
  float4 o1 = {a1.x + b1.x, a1.y + b1.y, a1.z + b1.z, a1.w + b1.w};
  float4* dst = (float4*)(out + (size_t)t * H_DIM + c);
  dst[0] = o0; dst[1] = o1;
}

// ================= fallback path (in-loop fp32->bf16 convert + atomics) =================
__global__ __launch_bounds__(256, 2)
void gemm1_kernel(const uint16_t* __restrict__ xg,
                  const float* __restrict__ gate, const float* __restrict__ up,
                  const int* __restrict__ ws_counts, const int* __restrict__ ws_offsets,
                  uint16_t* __restrict__ inter) {
  int e = blockIdx.z;
  int cnt = ws_counts[e];
  int rowTile = blockIdx.y;
  if (rowTile * 128 >= cnt) return;
  int off = ws_offsets[e];
  int colBase = blockIdx.x * 128;
  size_t rowBase = (size_t)off + (size_t)rowTile * 128;

  __shared__ uint16_t lA[128 * 64];
  __shared__ uint16_t lBg[128 * 64];
  __shared__ uint16_t lBu[128 * 64];

  int tid = threadIdx.x;
  int lane = tid & 63, wid = tid >> 6;
  int wm = (wid & 1) * 64, wn = (wid >> 1) * 64;
  int lcol = lane & 15, quad = lane >> 4;

  const float* gbase = gate + (size_t)e * I_DIM * H_DIM + (size_t)colBase * H_DIM;
  const float* ubase = up   + (size_t)e * I_DIM * H_DIM + (size_t)colBase * H_DIM;

  f32x4 accg[4][4], accu[4][4];
  f32x4 zero = {0.f, 0.f, 0.f, 0.f};
#pragma unroll
  for (int mi = 0; mi < 4; mi++)
#pragma unroll
    for (int ni = 0; ni < 4; ni++) { accg[mi][ni] = zero; accu[mi][ni] = zero; }

  for (int k0 = 0; k0 < H_DIM; k0 += 64) {
    __syncthreads();
#pragma unroll
    for (int rd = 0; rd < 4; rd++) {
      int chunkBase = rd * 256 + wid * 64;
      int chunk = chunkBase + lane;
      int row = chunk >> 3, kc = (chunk & 7) * 8;
      async_load16(xg + (rowBase + row) * H_DIM + k0 + kc, lA + chunkBase * 8);
    }
#pragma unroll
    for (int it = 0; it < 4; it++) {
      int c = it * 256 + tid;
      int row = c >> 3, kc = (c & 7) * 8;
      size_t soff = (size_t)row * H_DIM + k0 + kc;
      const float4* sg = (const float4*)(gbase + soff);
      float4 g0 = sg[0], g1 = sg[1];
      const float4* su = (const float4*)(ubase + soff);
      float4 u0 = su[0], u1 = su[1];
      uint4 og = { pk_bf16(g0.x, g0.y), pk_bf16(g0.z, g0.w), pk_bf16(g1.x, g1.y), pk_bf16(g1.z, g1.w) };
      uint4 ou = { pk_bf16(u0.x, u0.y), pk_bf16(u0.z, u0.w), pk_bf16(u1.x, u1.y), pk_bf16(u1.z, u1.w) };
      *(uint4*)(lBg + c * 8) = og;
      *(uint4*)(lBu + c * 8) = ou;
    }
    __syncthreads();
#pragma unroll
    for (int ks = 0; ks < 64; ks += 32) {
      int krow = ks + quad * 8;
      bf16x8 af[4], bg[4], bu[4];
#pragma unroll
      for (int mi = 0; mi < 4; mi++)
        af[mi] = *(const bf16x8*)(lA + (wm + mi * 16 + lcol) * 64 + krow);
#pragma unroll
      for (int ni = 0; ni < 4; ni++) {
        bg[ni] = *(const bf16x8*)(lBg + (wn + ni * 16 + lcol) * 64 + krow);
        bu[ni] = *(const bf16x8*)(lBu + (wn + ni * 16 + lcol) * 64 + krow);
      }
#pragma unroll
      for (int mi = 0; mi < 4; mi++)
#pragma unroll
        for (int ni = 0; ni < 4; ni++) {
          accg[mi][ni] = __builtin_amdgcn_mfma_f32_16x16x32_bf16(af[mi], bg[ni], accg[mi][ni], 0, 0, 0);
          accu[mi][ni] = __builtin_amdgcn_mfma_f32_16x16x32_bf16(af[mi], bu[ni], accu[mi][ni], 0, 0, 0);
        }
    }
  }
  int col0 = colBase + wn;
#pragma unroll
  for (int mi = 0; mi < 4; mi++) {
#pragma unroll
    for (int r = 0; r < 4; r++) {
      int localRow = rowTile * 128 + wm + mi * 16 + quad * 4 + r;
      if (localRow < cnt) {
        size_t prow = (size_t)off + localRow;
#pragma unroll
        for (int ni = 0; ni < 4; ni++) {
          float g = accg[mi][ni][r], u = accu[mi][ni][r];
          float v = (g / (1.f + __expf(-g))) * u;
          inter[prow * I_DIM + col0 + ni * 16 + lcol] = bf16_one(v);
        }
      }
    }
  }
}

__global__ __launch_bounds__(256, 2)
void gemm2_kernel(const uint16_t* __restrict__ inter, const float* __restrict__ down,
                  const int* __restrict__ ws_counts, const int* __restrict__ ws_offsets,
                  const int* __restrict__ tokid, const float* __restrict__ pairw,
                  float* __restrict__ out) {
  int e = blockIdx.z;
  int cnt = ws_counts[e];
  int rowTile = blockIdx.y;
  if (rowTile * 128 >= cnt) return;
  int off = ws_offsets[e];
  int colBase = blockIdx.x * 128;
  size_t rowBase = (size_t)off + (size_t)rowTile * 128;

  __shared__ uint16_t lA[128 * 64];
  __shared__ uint16_t lB[128 * 64];

  int tid = threadIdx.x;
  int lane = tid & 63, wid = tid >> 6;
  int wm = (wid & 1) * 64, wn = (wid >> 1) * 64;
  int lcol = lane & 15, quad = lane >> 4;

  const float* dbase = down + (size_t)e * H_DIM * I_DIM + (size_t)colBase * I_DIM;

  f32x4 acc[4][4];
  f32x4 zero = {0.f, 0.f, 0.f, 0.f};
#pragma unroll
  for (int mi = 0; mi < 4; mi++)
#pragma unroll
    for (int ni = 0; ni < 4; ni++) acc[mi][ni] = zero;

  for (int k0 = 0; k0 < I_DIM; k0 += 64) {
    __syncthreads();
#pragma unroll
    for (int rd = 0; rd < 4; rd++) {
      int chunkBase = rd * 256 + wid * 64;
      int chunk = chunkBase + lane;
      int row = chunk >> 3, kc = (chunk & 7) * 8;
      async_load16(inter + (rowBase + row) * I_DIM + k0 + kc, lA + chunkBase * 8);
    }
#pragma unroll
    for (int it = 0; it < 4; it++) {
      int c = it * 256 + tid;
      int row = c >> 3, kc = (c & 7) * 8;
      const float4* sd = (const float4*)(dbase + (size_t)row * I_DIM + k0 + kc);
      float4 d0 = sd[0], d1 = sd[1];
      uint4 od = { pk_bf16(d0.x, d0.y), pk_bf16(d0.z, d0.w), pk_bf16(d1.x, d1.y), pk_bf16(d1.z, d1.w) };
      *(uint4*)(lB + c * 8) = od;
    }
    __syncthreads();
#pragma unroll
    for (int ks = 0; ks < 64; ks += 32) {
      int krow = ks + quad * 8;
      bf16x8 af[4], bf[4];
#pragma unroll
      for (int mi = 0; mi < 4; mi++)
        af[mi] = *(const bf16x8*)(lA + (wm + mi * 16 + lcol) * 64 + krow);
#pragma unroll
      for (int ni = 0; ni < 4; ni++)
        bf[ni] = *(const bf16x8*)(lB + (wn + ni * 16 + lcol) * 64 + krow);
#pragma unroll
      for (int mi = 0; mi < 4; mi++)
#pragma unroll
        for (int ni = 0; ni < 4; ni++)
          acc[mi][ni] = __builtin_amdgcn_mfma_f32_16x16x32_bf16(af[mi], bf[ni], acc[mi][ni], 0, 0, 0);
    }
  }
  int col0 = colBase + wn;
#pragma unroll
  for (int mi = 0; mi < 4; mi++) {
#pragma unroll
    for (int r = 0; r < 4; r++) {
      int localRow = rowTile * 128 + wm + mi * 16 + quad * 4 + r;
      if (localRow < cnt) {
        size_t prow = (size_t)off + localRow;
        int t = tokid[prow];
        float w = pairw[prow];
        float* orow = out + (size_t)t * H_DIM + col0;
#pragma unroll
        for (int ni = 0; ni < 4; ni++)
          atomicAdd(orow + ni * 16 + lcol, acc[mi][ni][r] * w);
      }
    }
  }
}

extern "C" void kernel_launch(void* const* d_in, const int* in_sizes, int n_in,
                              void* d_out, int out_size, void* d_ws, size_t ws_size,
                              hipStream_t stream) {
  const float* x    = (const float*)d_in[0];
  const int*   eidx = (const int*)d_in[1];
  const float* ew   = (const float*)d_in[2];
  const float* gate = (const float*)d_in[3];
  const float* up   = (const float*)d_in[4];
  const float* down = (const float*)d_in[5];
  float* out = (float*)d_out;
  char* ws = (char*)d_ws;

  if (ws_size < WS_MIN_NEEDED) {
    hipMemsetAsync(d_out, 0, (size_t)NTOK * H_DIM * sizeof(float), stream);
    return;
  }

  int*      counts  = (int*)(ws + WS_COUNTS);
  int*      offsets = (int*)(ws + WS_OFFSETS);
  int*      tokid   = (int*)(ws + WS_TOKID);
  int*      slotOf  = (int*)(ws + WS_SLOT);
  float*    pairw   = (float*)(ws + WS_PAIRW);
  uint16_t* xg      = (uint16_t*)(ws + WS_XG);
  uint16_t* inter   = (uint16_t*)(ws + WS_INTER);

  route_kernel<<<1, 256, 0, stream>>>(eidx, ew, counts, offsets, tokid, slotOf, pairw);
  gather_cast_kernel<<<NPAIR, 256, 0, stream>>>(x, tokid, xg);

  if (ws_size >= WS_FULL) {
    float*    y  = (float*)(ws + WS_Y);
    uint16_t* gw = (uint16_t*)(ws + WS_GW);
    uint16_t* uw = (uint16_t*)(ws + WS_UW);
    uint16_t* dwp = (uint16_t*)(ws + WS_DW);

    cast3_kernel<<<dim3(1024, 3), 256, 0, stream>>>(gate, up, down, gw, uw, dwp);
    gemm1_pre_kernel<<<dim3(I_DIM / 128, NPAIR / 128, NEXP), 256, 0, stream>>>(
        xg, gw, uw, counts, offsets, inter);
    gemm2_pre_kernel<<<dim3(H_DIM / 128, NPAIR / 128, NEXP), 256, 0, stream>>>(
        inter, dwp, counts, offsets, pairw, (float*)(ws + WS_Y));
    combine_kernel<<<NTOK, 256, 0, stream>>>(y, slotOf, out);
  } else {
    hipMemsetAsync(d_out, 0, (size_t)NTOK * H_DIM * sizeof(float), stream);
    gemm1_kernel<<<dim3(I_DIM / 128, NPAIR / 128, NEXP), 256, 0, stream>>>(
        xg, gate, up, counts, offsets, inter);
    gemm2_kernel<<<dim3(H_DIM / 128, NPAIR / 128, NEXP), 256, 0, stream>>>(
        inter, down, counts, offsets, tokid, pairw, out);
  }
}

// Round 2
// 1333.299 us; speedup vs baseline: 1.0755x; 1.0755x over previous
//
#include <hip/hip_runtime.h>
#include <hip/hip_bf16.h>
#include <stdint.h>

// Problem constants: H=2048, I=4096, E=8, TOPK=2, B*S=4096
#define H_DIM 2048
#define I_DIM 4096
#define NEXP  8
#define NTOK  4096
#define NPAIR 8192
#define PAD_ROWS (NPAIR + 256)     // 256-row tiles may overrun last expert by <256

// Workspace layout (bytes)
#define MiB (1024ull * 1024ull)
#define WS_COUNTS   0ull
#define WS_OFFSETS  256ull
#define WS_TOKID    1024ull
#define WS_SLOT     (64ull * 1024)
#define WS_PAIRW    (128ull * 1024)
#define WS_XG       (1ull * MiB)            // PAD_ROWS*H*2B = 34.6 MB
#define WS_INTER    (36ull * MiB)           // PAD_ROWS*I*2B = 69.2 MB
#define WS_Y        (104ull * MiB)          // PAD_ROWS*H*4B = 69.2 MB
#define WS_GW       (176ull * MiB)          // E*I*H bf16 = 128 MiB
#define WS_UW       (304ull * MiB)
#define WS_DW       (432ull * MiB)
#define WS_FULL     (560ull * MiB)

typedef __attribute__((ext_vector_type(8))) short bf16x8;
typedef __attribute__((ext_vector_type(4))) float f32x4;

#if defined(__has_builtin)
#if __has_builtin(__builtin_amdgcn_cvt_pk_bf16_f32)
#define HAVE_CVT_PK 1
#endif
#endif

__device__ __forceinline__ uint32_t bf16_bits_rne(float x) {
  uint32_t u = __float_as_uint(x);
  return (u + 0x7FFFu + ((u >> 16) & 1u)) >> 16;
}
__device__ __forceinline__ uint32_t pk_bf16(float a, float b) {
#ifdef HAVE_CVT_PK
  auto r = __builtin_amdgcn_cvt_pk_bf16_f32(a, b);
  return __builtin_bit_cast(uint32_t, r);
#else
  return bf16_bits_rne(a) | (bf16_bits_rne(b) << 16);
#endif
}
__device__ __forceinline__ uint16_t bf16_one(float x) {
  return (uint16_t)(pk_bf16(x, x) & 0xFFFFu);
}

// async global->LDS, 16B/lane: lane i lands at lds_base + 16*i (base wave-uniform)
__device__ __forceinline__ void async_load16(const void* g, void* l) {
  __builtin_amdgcn_global_load_lds(
      (const __attribute__((address_space(1))) void*)g,
      (__attribute__((address_space(3))) void*)l, 16, 0, 0);
}

#define WAIT_VM6()  do { asm volatile("s_waitcnt vmcnt(6)" ::: "memory"); __builtin_amdgcn_sched_barrier(0); } while (0)
#define WAIT_VM0()  do { asm volatile("s_waitcnt vmcnt(0)" ::: "memory"); __builtin_amdgcn_sched_barrier(0); } while (0)
#define BARRIER()   do { __builtin_amdgcn_s_barrier(); asm volatile("" ::: "memory"); } while (0)

// ---------------- routing ----------------
__global__ void route_kernel(const int* __restrict__ idx, const float* __restrict__ wts,
                             int* __restrict__ ws_counts, int* __restrict__ ws_offsets,
                             int* __restrict__ tokid, int* __restrict__ slotOf,
                             float* __restrict__ pairw) {
  __shared__ int s_cnt[NEXP], s_off[NEXP], s_cur[NEXP];
  int tid = threadIdx.x;
  if (tid < NEXP) s_cnt[tid] = 0;
  __syncthreads();
  for (int p = tid; p < NPAIR; p += 256) atomicAdd(&s_cnt[idx[p]], 1);
  __syncthreads();
  if (tid == 0) {
    int acc = 0;
    for (int e = 0; e < NEXP; e++) { s_off[e] = acc; s_cur[e] = acc; acc += s_cnt[e]; }
  }
  __syncthreads();
  for (int p = tid; p < NPAIR; p += 256) {
    int e = idx[p];
    int slot = atomicAdd(&s_cur[e], 1);
    tokid[slot] = p >> 1;
    slotOf[p] = slot;
    pairw[slot] = wts[p];
  }
  if (tid < NEXP) { ws_counts[tid] = s_cnt[tid]; ws_offsets[tid] = s_off[tid]; }
}

// ---------------- gather routed rows of x, fp32 -> bf16 ----------------
__global__ void gather_cast_kernel(const float* __restrict__ x, const int* __restrict__ tokid,
                                   uint16_t* __restrict__ xg) {
  int p = blockIdx.x;
  int t = tokid[p];
  int c = threadIdx.x * 8;
  const float4* src = (const float4*)(x + (size_t)t * H_DIM + c);
  float4 v0 = src[0], v1 = src[1];
  uint4 o;
  o.x = pk_bf16(v0.x, v0.y); o.y = pk_bf16(v0.z, v0.w);
  o.z = pk_bf16(v1.x, v1.y); o.w = pk_bf16(v1.z, v1.w);
  *(uint4*)(xg + (size_t)p * H_DIM + c) = o;
}

// ---------------- one-shot weight cast fp32 -> bf16 ----------------
__global__ void cast3_kernel(const float* __restrict__ g, const float* __restrict__ u,
                             const float* __restrict__ d,
                             uint16_t* __restrict__ gw, uint16_t* __restrict__ uw,
                             uint16_t* __restrict__ dw) {
  const float* src = blockIdx.y == 0 ? g : (blockIdx.y == 1 ? u : d);
  uint16_t*    dst = blockIdx.y == 0 ? gw : (blockIdx.y == 1 ? uw : dw);
  const long long n8 = (long long)NEXP * I_DIM * H_DIM / 8;
  long long stride = (long long)gridDim.x * blockDim.x;
  for (long long i = (long long)blockIdx.x * blockDim.x + threadIdx.x; i < n8; i += stride) {
    const float4* s = (const float4*)(src + i * 8);
    float4 a = s[0], b = s[1];
    uint4 o = { pk_bf16(a.x, a.y), pk_bf16(a.z, a.w), pk_bf16(b.x, b.y), pk_bf16(b.z, b.w) };
    *(uint4*)(dst + i * 8) = o;
  }
}

// =====================================================================================
// GEMM1 v2: 256x64 tile (dual-B gate/up), BK=64, 8 waves (4M x 2N), triple-buffered LDS,
// counted vmcnt(6), one raw barrier per K-tile, XOR-swizzled LDS (source-side permuted).
// =====================================================================================
#define T1_A    (256 * 64)
#define T1_B    (64 * 64)
#define T1_ELE  (T1_A + 2 * T1_B)   // 24576 elems = 48KB

__global__ __launch_bounds__(512, 1)
void gemm1_v2(const uint16_t* __restrict__ xg,
              const uint16_t* __restrict__ gw, const uint16_t* __restrict__ uw,
              const int* __restrict__ ws_counts, const int* __restrict__ ws_offsets,
              uint16_t* __restrict__ inter) {
  int e = blockIdx.z;
  int cnt = ws_counts[e];
  int rowTile = blockIdx.y;
  if (rowTile * 256 >= cnt) return;
  int off = ws_offsets[e];
  int colBase = blockIdx.x * 64;
  size_t rowBase = (size_t)off + (size_t)rowTile * 256;

  __shared__ uint16_t lds[3 * T1_ELE];    // 144 KB

  int tid = threadIdx.x, lane = tid & 63, w = tid >> 6;
  int r8 = lane >> 3;                      // row within 8-row chunk
  int gsw = ((lane & 7) ^ r8) << 3;        // pre-swizzled source col (elements)

  // per-lane global sources (advance by kt*64 elems per K-tile; K is contiguous)
  const uint16_t* srcA[4];
#pragma unroll
  for (int c = 0; c < 4; c++)
    srcA[c] = xg + (rowBase + (size_t)(w * 32 + c * 8 + r8)) * H_DIM + gsw;
  const uint16_t* srcG = gw + ((size_t)e * I_DIM + colBase + w * 8 + r8) * H_DIM + gsw;
  const uint16_t* srcU = uw + ((size_t)e * I_DIM + colBase + w * 8 + r8) * H_DIM + gsw;

  const int dA = w * 2048;                 // wave's A region (elems)
  const int dG = T1_A + w * 512;           // wave's Bg region
  const int dU = T1_A + T1_B + w * 512;    // wave's Bu region

  f32x4 accg[4][2], accu[4][2];
  f32x4 zero = {0.f, 0.f, 0.f, 0.f};
#pragma unroll
  for (int mi = 0; mi < 4; mi++)
#pragma unroll
    for (int ni = 0; ni < 2; ni++) { accg[mi][ni] = zero; accu[mi][ni] = zero; }

  auto STG = [&](int kt, int b) {
    uint16_t* lb = lds + b * T1_ELE;
    int ko = kt * 64;
#pragma unroll
    for (int c = 0; c < 4; c++) async_load16(srcA[c] + ko, lb + dA + c * 512);
    async_load16(srcG + ko, lb + dG);
    async_load16(srcU + ko, lb + dU);
  };

  STG(0, 0); STG(1, 1);
  WAIT_VM6();        // K-tile 0 landed (own 6 oldest loads)
  BARRIER();

  int wr = w >> 1, wc = w & 1;
  int wm = wr * 64, wn = wc * 32;
  int lcol = lane & 15, quad = lane >> 4;
  int sx = (lcol & 7) << 3;                // read-side swizzle

  const int NT = H_DIM / 64;               // 32
  for (int t = 0; t < NT; ++t) {
    if (t + 2 < NT) STG(t + 2, (t + 2) % 3);
    const uint16_t* lb = lds + (t % 3) * T1_ELE;
#pragma unroll
    for (int ks = 0; ks < 2; ks++) {
      int krs = (ks * 32 + quad * 8) ^ sx;
      bf16x8 af[4], bg_[2], bu_[2];
#pragma unroll
      for (int mi = 0; mi < 4; mi++)
        af[mi] = *(const bf16x8*)(lb + (wm + mi * 16 + lcol) * 64 + krs);
#pragma unroll
      for (int ni = 0; ni < 2; ni++) {
        bg_[ni] = *(const bf16x8*)(lb + T1_A + (wn + ni * 16 + lcol) * 64 + krs);
        bu_[ni] = *(const bf16x8*)(lb + T1_A + T1_B + (wn + ni * 16 + lcol) * 64 + krs);
      }
      __builtin_amdgcn_s_setprio(1);
#pragma unroll
      for (int mi = 0; mi < 4; mi++)
#pragma unroll
        for (int ni = 0; ni < 2; ni++) {
          accg[mi][ni] = __builtin_amdgcn_mfma_f32_16x16x32_bf16(af[mi], bg_[ni], accg[mi][ni], 0, 0, 0);
          accu[mi][ni] = __builtin_amdgcn_mfma_f32_16x16x32_bf16(af[mi], bu_[ni], accu[mi][ni], 0, 0, 0);
        }
      __builtin_amdgcn_s_setprio(0);
    }
    if (t + 2 < NT) { WAIT_VM6(); } else { WAIT_VM0(); }
    BARRIER();
  }

  // epilogue: silu(g)*u -> bf16 inter.  C layout: col=lane&15, row=quad*4+reg
  int col0 = colBase + wn;
#pragma unroll
  for (int mi = 0; mi < 4; mi++) {
#pragma unroll
    for (int r = 0; r < 4; r++) {
      int localRow = rowTile * 256 + wm + mi * 16 + quad * 4 + r;
      if (localRow < cnt) {
        size_t prow = (size_t)off + localRow;
#pragma unroll
        for (int ni = 0; ni < 2; ni++) {
          float g = accg[mi][ni][r], u = accu[mi][ni][r];
          float v = (g / (1.f + __expf(-g))) * u;
          inter[prow * I_DIM + col0 + ni * 16 + lcol] = bf16_one(v);
        }
      }
    }
  }
}

// =====================================================================================
// GEMM2 v2: 256x128 tile, BK=64, same schedule. Output scaled by pairw to per-pair y.
// =====================================================================================
#define T2_A    (256 * 64)
#define T2_B    (128 * 64)
#define T2_ELE  (T2_A + T2_B)       // 24576 elems = 48KB

__global__ __launch_bounds__(512, 1)
void gemm2_v2(const uint16_t* __restrict__ inter, const uint16_t* __restrict__ dw,
              const int* __restrict__ ws_counts, const int* __restrict__ ws_offsets,
              const float* __restrict__ pairw, float* __restrict__ y) {
  int e = blockIdx.z;
  int cnt = ws_counts[e];
  int rowTile = blockIdx.y;
  if (rowTile * 256 >= cnt) return;
  int off = ws_offsets[e];
  int colBase = blockIdx.x * 128;
  size_t rowBase = (size_t)off + (size_t)rowTile * 256;

  __shared__ uint16_t lds[3 * T2_ELE];    // 144 KB

  int tid = threadIdx.x, lane = tid & 63, w = tid >> 6;
  int r8 = lane >> 3;
  int gsw = ((lane & 7) ^ r8) << 3;

  const uint16_t* srcA[4];
#pragma unroll
  for (int c = 0; c < 4; c++)
    srcA[c] = inter + (rowBase + (size_t)(w * 32 + c * 8 + r8)) * I_DIM + gsw;
  const uint16_t* srcB[2];
#pragma unroll
  for (int c = 0; c < 2; c++)
    srcB[c] = dw + ((size_t)e * H_DIM + colBase + w * 16 + c * 8 + r8) * I_DIM + gsw;

  const int dA = w * 2048;
  const int dB = T2_A + w * 1024;

  f32x4 acc[4][4];
  f32x4 zero = {0.f, 0.f, 0.f, 0.f};
#pragma unroll
  for (int mi = 0; mi < 4; mi++)
#pragma unroll
    for (int ni = 0; ni < 4; ni++) acc[mi][ni] = zero;

  auto STG = [&](int kt, int b) {
    uint16_t* lb = lds + b * T2_ELE;
    int ko = kt * 64;
#pragma unroll
    for (int c = 0; c < 4; c++) async_load16(srcA[c] + ko, lb + dA + c * 512);
#pragma unroll
    for (int c = 0; c < 2; c++) async_load16(srcB[c] + ko, lb + dB + c * 512);
  };

  STG(0, 0); STG(1, 1);
  WAIT_VM6();
  BARRIER();

  int wr = w >> 1, wc = w & 1;
  int wm = wr * 64, wn = wc * 64;
  int lcol = lane & 15, quad = lane >> 4;
  int sx = (lcol & 7) << 3;

  const int NT = I_DIM / 64;               // 64
  for (int t = 0; t < NT; ++t) {
    if (t + 2 < NT) STG(t + 2, (t + 2) % 3);
    const uint16_t* lb = lds + (t % 3) * T2_ELE;
#pragma unroll
    for (int ks = 0; ks < 2; ks++) {
      int krs = (ks * 32 + quad * 8) ^ sx;
      bf16x8 af[4], bf_[4];
#pragma unroll
      for (int mi = 0; mi < 4; mi++)
        af[mi] = *(const bf16x8*)(lb + (wm + mi * 16 + lcol) * 64 + krs);
#pragma unroll
      for (int ni = 0; ni < 4; ni++)
        bf_[ni] = *(const bf16x8*)(lb + T2_A + (wn + ni * 16 + lcol) * 64 + krs);
      __builtin_amdgcn_s_setprio(1);
#pragma unroll
      for (int mi = 0; mi < 4; mi++)
#pragma unroll
        for (int ni = 0; ni < 4; ni++)
          acc[mi][ni] = __builtin_amdgcn_mfma_f32_16x16x32_bf16(af[mi], bf_[ni], acc[mi][ni], 0, 0, 0);
      __builtin_amdgcn_s_setprio(0);
    }
    if (t + 2 < NT) { WAIT_VM6(); } else { WAIT_VM0(); }
    BARRIER();
  }

  int col0 = colBase + wn;
#pragma unroll
  for (int mi = 0; mi < 4; mi++) {
#pragma unroll
    for (int r = 0; r < 4; r++) {
      int localRow = rowTile * 256 + wm + mi * 16 + quad * 4 + r;
      if (localRow < cnt) {
        size_t prow = (size_t)off + localRow;
        float wgt = pairw[prow];
        float* yr = y + prow * H_DIM + col0;
#pragma unroll
        for (int ni = 0; ni < 4; ni++)
          yr[ni * 16 + lcol] = acc[mi][ni][r] * wgt;
      }
    }
  }
}

// ---------------- combine: out[t] = y[slot(2t)] + y[slot(2t+1)] ----------------
__global__ void combine_kernel(const float* __restrict__ y, const int* __restrict__ slotOf,
                               float* __restrict__ out) {
  int t = blockIdx.x;
  int s0 = slotOf[2 * t], s1 = slotOf[2 * t + 1];
  int c = threadIdx.x * 8;
  const float4* a = (const float4*)(y + (size_t)s0 * H_DIM + c);
  const float4* b = (const float4*)(y + (size_t)s1 * H_DIM + c);
  float4 a0 = a[0], a1 = a[1], b0 = b[0], b1 = b[1];
  float4 o0 = {a0.x + b0.x, a0.y + b0.y, a0.z + b0.z, a0.w + b0.w};
  float4 o1 = {a1.x + b1.x, a1.y + b1.y, a1.z + b1.z, a1.w + b1.w};
  float4* dst = (float4*)(out + (size_t)t * H_DIM + c);
  dst[0] = o0; dst[1] = o1;
}

extern "C" void kernel_launch(void* const* d_in, const int* in_sizes, int n_in,
                              void* d_out, int out_size, void* d_ws, size_t ws_size,
                              hipStream_t stream) {
  const float* x    = (const float*)d_in[0];
  const int*   eidx = (const int*)d_in[1];
  const float* ew   = (const float*)d_in[2];
  const float* gate = (const float*)d_in[3];
  const float* up   = (const float*)d_in[4];
  const float* down = (const float*)d_in[5];
  float* out = (float*)d_out;
  char* ws = (char*)d_ws;

  if (ws_size < WS_FULL) {
    hipMemsetAsync(d_out, 0, (size_t)NTOK * H_DIM * sizeof(float), stream);
    return;
  }

  int*      counts  = (int*)(ws + WS_COUNTS);
  int*      offsets = (int*)(ws + WS_OFFSETS);
  int*      tokid   = (int*)(ws + WS_TOKID);
  int*      slotOf  = (int*)(ws + WS_SLOT);
  float*    pairw   = (float*)(ws + WS_PAIRW);
  uint16_t* xg      = (uint16_t*)(ws + WS_XG);
  uint16_t* inter   = (uint16_t*)(ws + WS_INTER);
  float*    y       = (float*)(ws + WS_Y);
  uint16_t* gw      = (uint16_t*)(ws + WS_GW);
  uint16_t* uw      = (uint16_t*)(ws + WS_UW);
  uint16_t* dwp     = (uint16_t*)(ws + WS_DW);

  route_kernel<<<1, 256, 0, stream>>>(eidx, ew, counts, offsets, tokid, slotOf, pairw);
  gather_cast_kernel<<<NPAIR, 256, 0, stream>>>(x, tokid, xg);
  cast3_kernel<<<dim3(2048, 3), 256, 0, stream>>>(gate, up, down, gw, uw, dwp);

  gemm1_v2<<<dim3(I_DIM / 64, NPAIR / 256, NEXP), 512, 0, stream>>>(
      xg, gw, uw, counts, offsets, inter);
  gemm2_v2<<<dim3(H_DIM / 128, NPAIR / 256, NEXP), 512, 0, stream>>>(
      inter, dwp, counts, offsets, pairw, y);
  combine_kernel<<<NTOK, 256, 0, stream>>>(y, slotOf, out);
}